// Round 5
// baseline (374.086 us; speedup 1.0000x reference)
//
#include <hip/hip_runtime.h>
#include <stdint.h>

typedef unsigned short u16;
typedef __attribute__((ext_vector_type(8))) short bf16x8;    // 8 bf16 = 4 VGPRs
typedef __attribute__((ext_vector_type(4))) float f32x4;
typedef __attribute__((ext_vector_type(16))) float f32x16;

#define NUM_B 2
#define SEQ   2048
#define NH    16
#define HD    128
#define EMB   2048      // NH*HD
#define N3    6144      // 3*EMB
#define MM    4096      // NUM_B*SEQ
#define QT    64        // flash q-rows per block (2 waves)
#define WQ    32        // flash q-rows per wave
#define KT    32        // flash keys per k-tile
#define NTILE (SEQ / KT)

__device__ __forceinline__ u16 f2bf(float f) {
  union { float f; unsigned u; } c; c.f = f;
  return (u16)((c.u + 0x7FFFu + ((c.u >> 16) & 1u)) >> 16);   // RNE
}
__device__ __forceinline__ void async16(const void* g, void* l) {
  __builtin_amdgcn_global_load_lds(
      (const __attribute__((address_space(1))) void*)g,
      (__attribute__((address_space(3))) void*)l, 16, 0, 0);
}

// ---------------- prep kernels ----------------

__global__ void k_cvt_bf16(const float* __restrict__ in, u16* __restrict__ out, int n4) {
  int i = blockIdx.x * blockDim.x + threadIdx.x;
  if (i >= n4) return;
  const float4 v = ((const float4*)in)[i];
  ushort4 o;
  o.x = f2bf(v.x); o.y = f2bf(v.y); o.z = f2bf(v.z); o.w = f2bf(v.w);
  ((ushort4*)out)[i] = o;
}

// W [EMB][N3] fp32 -> Wt [N3][EMB] bf16
__global__ void k_transpose_w(const float* __restrict__ W, u16* __restrict__ Wt) {
  __shared__ float t[32][33];
  int n0 = blockIdx.x * 32, k0 = blockIdx.y * 32;
  int tx = threadIdx.x, ty = threadIdx.y;
  #pragma unroll
  for (int i = ty; i < 32; i += 8)
    t[i][tx] = W[(size_t)(k0 + i) * N3 + n0 + tx];
  __syncthreads();
  #pragma unroll
  for (int i = ty; i < 32; i += 8)
    Wt[(size_t)(n0 + i) * EMB + k0 + tx] = f2bf(t[tx][i]);
}

// sincos table for t = s*HD + d; double-precision sincos matches numpy fp32 tables
__global__ void k_sincos(float2* __restrict__ tab) {
  int i = blockIdx.x * blockDim.x + threadIdx.x;   // 0 .. SEQ*HD-1
  double t = (double)i;
  tab[i] = make_float2((float)cos(t), (float)sin(t));
}

// ---------------- QKV GEMM v2: 32x32x16 MFMA, conflict-free swizzled LDS ----------------
// 128x128 tile, BK=32, wave tile = 32 rows x 128 cols (1x4 of 32x32 MFMA).
// LDS rows are 64B (4x16B granules); frag reads XOR granule with (row>>1)&3 so a
// 16-lane phase covers all 32 banks (2 lanes/bank = free). global_load_lds can't
// scatter on the LDS side, so the swizzle permutes the GLOBAL source granule
// (same 64B segment -> coalescing unchanged), LDS dest stays contiguous.
// Epilogue: q/k get RoPE (+log2e/sqrt(D) scale on q), v transposed to [B,H,D,S].
__global__ __launch_bounds__(256, 2) void k_gemm_qkv(
    const u16* __restrict__ xb, const u16* __restrict__ wt,
    const float* __restrict__ bias, const float2* __restrict__ tab,
    u16* __restrict__ qb, u16* __restrict__ kb, u16* __restrict__ vbt)
{
  __shared__ __align__(16) u16 lsA[128 * 32];
  __shared__ __align__(16) u16 lsB[128 * 32];
  const int tid = threadIdx.x;
  const int wave = tid >> 6, lane = tid & 63;
  const int l31 = lane & 31, hl = lane >> 5;
  const int m0 = blockIdx.y * 128, n0 = blockIdx.x * 128;

  f32x16 acc[4];
  #pragma unroll
  for (int j = 0; j < 4; ++j)
    #pragma unroll
    for (int r = 0; r < 16; ++r) acc[j][r] = 0.f;

  const int arow = wave * 32 + l31;
  const int aswz = (arow >> 1) & 3;

  for (int kt = 0; kt < EMB; kt += 32) {
    __syncthreads();
    #pragma unroll
    for (int i = 0; i < 2; ++i) {
      int c = tid + i * 256;                 // 16B chunk; row = c>>2
      int row = c >> 2;
      int g = (c & 3) ^ ((row >> 1) & 3);    // global-side granule swizzle
      async16(xb + (size_t)(m0 + row) * EMB + kt + g * 8, lsA + c * 8);
      async16(wt + (size_t)(n0 + row) * EMB + kt + g * 8, lsB + c * 8);
    }
    __syncthreads();
    // A frags: A[m = arow][k = ks*16 + hl*8 ..+7]
    bf16x8 af[2];
    #pragma unroll
    for (int ks = 0; ks < 2; ++ks)
      af[ks] = *(const bf16x8*)(lsA + arow * 32 + ((ks * 2 + hl) ^ aswz) * 8);
    // B frags: B[k][n = j*32+l31] = Wt[n][k]
    bf16x8 bfr[2][4];
    #pragma unroll
    for (int j = 0; j < 4; ++j) {
      int brow = j * 32 + l31;
      int bswz = (brow >> 1) & 3;
      #pragma unroll
      for (int ks = 0; ks < 2; ++ks)
        bfr[ks][j] = *(const bf16x8*)(lsB + brow * 32 + ((ks * 2 + hl) ^ bswz) * 8);
    }
    #pragma unroll
    for (int ks = 0; ks < 2; ++ks)
      #pragma unroll
      for (int j = 0; j < 4; ++j)
        acc[j] = __builtin_amdgcn_mfma_f32_32x32x16_bf16(af[ks], bfr[ks][j], acc[j], 0, 0, 0);
  }

  // C/D layout (m74/m101): col = lane&31, row = (reg&3) + 8*(reg>>2) + 4*(lane>>5)
  const int w = n0 >> 11;              // 0=q, 1=k, 2=v
  const int h = (n0 & 2047) >> 7;
  float bb[4];
  #pragma unroll
  for (int j = 0; j < 4; ++j) bb[j] = bias[n0 + j * 32 + l31];

  if (w == 2) {
    // V -> [B,H,D,S]; reg-quads give 4 consecutive seq rows -> packed ushort4
    #pragma unroll
    for (int j = 0; j < 4; ++j) {
      int d = j * 32 + l31;
      #pragma unroll
      for (int rg = 0; rg < 4; ++rg) {
        int mg0 = m0 + wave * 32 + rg * 8 + hl * 4;
        int b = mg0 >> 11, s0 = mg0 & 2047;
        ushort4 pk;
        pk.x = f2bf(acc[j][rg * 4 + 0] + bb[j]);
        pk.y = f2bf(acc[j][rg * 4 + 1] + bb[j]);
        pk.z = f2bf(acc[j][rg * 4 + 2] + bb[j]);
        pk.w = f2bf(acc[j][rg * 4 + 3] + bb[j]);
        *(ushort4*)(vbt + ((size_t)(b * NH + h) * HD + d) * SEQ + s0) = pk;
      }
    }
  } else {
    u16* basep = (w == 0) ? qb : kb;
    const float qs = (w == 0) ? 0.12751569843736827f : 1.0f;  // log2(e)/sqrt(128) into q
    #pragma unroll
    for (int j = 0; j < 2; ++j) {
      int d1 = j * 32 + l31;                // pair lives in tile j+2 (d1+64), same lane
      #pragma unroll
      for (int reg = 0; reg < 16; ++reg) {
        int crow = (reg & 3) + 8 * (reg >> 2) + 4 * hl;
        int mg = m0 + wave * 32 + crow;
        int b = mg >> 11, s = mg & 2047;
        float c1 = acc[j][reg]     + bb[j];
        float c2 = acc[j + 2][reg] + bb[j + 2];
        float2 s1 = tab[s * HD + d1];
        float2 s2 = tab[s * HD + d1 + 64];
        u16* dst = basep + ((size_t)(b * NH + h) * SEQ + s) * HD;
        dst[d1]      = f2bf((c1 * s1.x - c2 * s1.y) * qs);
        dst[d1 + 64] = f2bf((c2 * s2.x + c1 * s2.y) * qs);
      }
    }
  }
}

// ---------------- flash attention v3 (unchanged from round 4) ----------------
__global__ __launch_bounds__(128, 2) void k_flash(
    const u16* __restrict__ qb, const u16* __restrict__ kb,
    const u16* __restrict__ vbt, float* __restrict__ out)
{
  __shared__ __align__(16) u16 lsK[2][KT * HD];   // [key][d] 16B-grp ^= key&7    (8 KB x2)
  __shared__ __align__(16) u16 lsV[2][HD * KT];   // [d][key] 16B-grp ^= (d>>1)&3 (8 KB x2)
  __shared__ __align__(16) u16 lsP[2][WQ * KT];   // per-wave [qrow][key], 8B-grp ^= row&6

  const int tid = threadIdx.x;            // 0..127
  const int wave = tid >> 6, lane = tid & 63;
  const int lq = lane & 15, lr = lane >> 4;
  const int q0 = blockIdx.x * QT;
  const int bh = blockIdx.y;
  const u16* Qg = qb + ((size_t)bh * SEQ + q0 + wave * WQ) * HD;
  const u16* Kg = kb + (size_t)bh * SEQ * HD;
  const u16* Vg = vbt + (size_t)bh * HD * SEQ;

  auto stage = [&](int tile, int buf) {
    const int k0 = tile * KT;
    #pragma unroll
    for (int i = 0; i < 4; ++i) {
      int c = tid + i * 128;
      int key = c >> 4, grp = c & 15;
      async16(Kg + (size_t)(k0 + key) * HD + ((grp ^ (key & 7)) * 8), lsK[buf] + c * 8);
    }
    #pragma unroll
    for (int i = 0; i < 4; ++i) {
      int c = tid + i * 128;
      int d = c >> 2, g2 = c & 3;
      async16(Vg + (size_t)d * SEQ + k0 + ((g2 ^ ((d >> 1) & 3)) * 8), lsV[buf] + c * 8);
    }
  };

  stage(0, 0);

  bf16x8 qf[2][4];
  #pragma unroll
  for (int qq = 0; qq < 2; ++qq)
    #pragma unroll
    for (int ks = 0; ks < 4; ++ks)
      qf[qq][ks] = *(const bf16x8*)(Qg + (size_t)(qq * 16 + lq) * HD + ks * 32 + lr * 8);

  f32x4 acc_o[2][8];
  float lsum[2] = {0.f, 0.f};
  #pragma unroll
  for (int mb = 0; mb < 2; ++mb)
    #pragma unroll
    for (int nb = 0; nb < 8; ++nb) acc_o[mb][nb] = f32x4{0.f, 0.f, 0.f, 0.f};

  for (int t = 0; t < NTILE; ++t) {
    const int p = t & 1;
    __syncthreads();
    if (t + 1 < NTILE) stage(t + 1, 1 - p);

    // S^T = K Q^T : 32 keys x 32 q-rows per wave
    f32x4 sacc[2][2];
    #pragma unroll
    for (int kbi = 0; kbi < 2; ++kbi)
      #pragma unroll
      for (int qq = 0; qq < 2; ++qq) sacc[kbi][qq] = f32x4{0.f, 0.f, 0.f, 0.f};
    #pragma unroll
    for (int ks = 0; ks < 4; ++ks) {
      bf16x8 kf[2];
      #pragma unroll
      for (int kbi = 0; kbi < 2; ++kbi) {
        int key = kbi * 16 + lq;
        int g = (ks * 4 + lr) ^ (key & 7);
        kf[kbi] = *(const bf16x8*)(lsK[p] + key * HD + g * 8);
      }
      #pragma unroll
      for (int kbi = 0; kbi < 2; ++kbi)
        #pragma unroll
        for (int qq = 0; qq < 2; ++qq)
          sacc[kbi][qq] = __builtin_amdgcn_mfma_f32_16x16x32_bf16(kf[kbi], qf[qq][ks], sacc[kbi][qq], 0, 0, 0);
    }

    // P = exp2(S); packed b64 writes (4 consecutive keys/lane)
    #pragma unroll
    for (int kbi = 0; kbi < 2; ++kbi)
      #pragma unroll
      for (int qq = 0; qq < 2; ++qq) {
        float p0 = __builtin_amdgcn_exp2f(sacc[kbi][qq][0]);
        float p1 = __builtin_amdgcn_exp2f(sacc[kbi][qq][1]);
        float p2 = __builtin_amdgcn_exp2f(sacc[kbi][qq][2]);
        float p3 = __builtin_amdgcn_exp2f(sacc[kbi][qq][3]);
        lsum[qq] += (p0 + p1) + (p2 + p3);
        int row = qq * 16 + lq;
        int g = kbi * 4 + lr;
        int gp = g ^ (row & 6);
        uint2 pk;
        pk.x = (uint32_t)f2bf(p0) | ((uint32_t)f2bf(p1) << 16);
        pk.y = (uint32_t)f2bf(p2) | ((uint32_t)f2bf(p3) << 16);
        *(uint2*)(lsP[wave] + row * KT + gp * 4) = pk;
      }

    // O += P V
    bf16x8 ap[2];
    #pragma unroll
    for (int mb = 0; mb < 2; ++mb) {
      int row = mb * 16 + lq;
      int gp = (2 * lr) ^ (row & 6);
      ap[mb] = *(const bf16x8*)(lsP[wave] + row * KT + gp * 4);
    }
    #pragma unroll
    for (int nb = 0; nb < 8; ++nb) {
      int d = nb * 16 + lq;
      int g2 = lr ^ ((d >> 1) & 3);
      bf16x8 bv = *(const bf16x8*)(lsV[p] + d * KT + g2 * 8);
      #pragma unroll
      for (int mb = 0; mb < 2; ++mb)
        acc_o[mb][nb] = __builtin_amdgcn_mfma_f32_16x16x32_bf16(ap[mb], bv, acc_o[mb][nb], 0, 0, 0);
    }
  }

  float inv[2];
  #pragma unroll
  for (int qq = 0; qq < 2; ++qq) {
    float s = lsum[qq];
    s += __shfl_xor(s, 16);
    s += __shfl_xor(s, 32);
    inv[qq] = 1.0f / s;
  }
  const int b = bh >> 4, h = bh & 15;
  #pragma unroll
  for (int mb = 0; mb < 2; ++mb)
    #pragma unroll
    for (int r = 0; r < 4; ++r) {
      float iv = __shfl(inv[mb], lr * 4 + r);
      int row = wave * WQ + mb * 16 + lr * 4 + r;
      int sq = q0 + row;
      float* op = out + (((size_t)b * SEQ + sq) * NH + h) * HD;
      #pragma unroll
      for (int nb = 0; nb < 8; ++nb)
        op[nb * 16 + lq] = acc_o[mb][nb][r] * iv;
    }
}

// ---------------- launch ----------------

extern "C" void kernel_launch(void* const* d_in, const int* in_sizes, int n_in,
                              void* d_out, int out_size, void* d_ws, size_t ws_size,
                              hipStream_t stream) {
  (void)in_sizes; (void)n_in; (void)out_size; (void)ws_size;
  const float* x    = (const float*)d_in[0];
  const float* W    = (const float*)d_in[1];
  const float* bias = (const float*)d_in[2];
  float* out = (float*)d_out;

  char* p = (char*)d_ws;
  u16* xb  = (u16*)p;  p += (size_t)MM * EMB * 2;                     // 16.8 MB
  u16* wt  = (u16*)p;  p += (size_t)N3 * EMB * 2;                     // 25.2 MB
  u16* qb  = (u16*)p;  p += (size_t)NUM_B * NH * SEQ * HD * 2;        // 16.8 MB
  u16* kb  = (u16*)p;  p += (size_t)NUM_B * NH * SEQ * HD * 2;        // 16.8 MB
  u16* vbt = (u16*)p;  p += (size_t)NUM_B * NH * SEQ * HD * 2;        // 16.8 MB
  float2* tab = (float2*)p;                                           // 2.1 MB

  k_cvt_bf16<<<(MM * EMB / 4 + 255) / 256, 256, 0, stream>>>(x, xb, MM * EMB / 4);
  k_transpose_w<<<dim3(N3 / 32, EMB / 32), dim3(32, 8), 0, stream>>>(W, wt);
  k_sincos<<<(SEQ * HD) / 256, 256, 0, stream>>>(tab);
  k_gemm_qkv<<<dim3(N3 / 128, MM / 128), 256, 0, stream>>>(xb, wt, bias, tab, qb, kb, vbt);
  k_flash<<<dim3(SEQ / QT, NUM_B * NH), 128, 0, stream>>>(qb, kb, vbt, out);
}